// Round 1
// baseline (2356.651 us; speedup 1.0000x reference)
//
#include <hip/hip_runtime.h>
#include <hip/hip_bf16.h>

// Problem constants
#define NB 65536
#define DIN 768
#define DH 512
#define DZ 64

// ---------------------------------------------------------------------------
// Tiled fp32 GEMM: C[M,N] = A[M,K] @ B[K,N] + bias, optional ReLU,
// optional fused (C - X)^2 loss accumulation (dec2), optional zh B-layout
// (B = preW[3][512][64] read as [512][192]).
// BM=128, BN=128, BK=16, 256 threads, 8x8 per thread. M must be %128.
// ---------------------------------------------------------------------------
template<bool RELU, bool ZHB, bool LOSS>
__global__ __launch_bounds__(256)
void gemm_k(const float* __restrict__ A, const float* __restrict__ Bm,
            const float* __restrict__ bias, float* __restrict__ C,
            int N, int K, const float* __restrict__ X, double* __restrict__ lacc)
{
    __shared__ __align__(16) float a_lds[16 * 132];
    __shared__ __align__(16) float b_lds[16 * 132];

    const int t  = threadIdx.x;
    const int tx = t & 15, ty = t >> 4;
    const int row0 = blockIdx.y * 128;
    const int col0 = blockIdx.x * 128;

    float acc[8][8];
#pragma unroll
    for (int i = 0; i < 8; ++i)
#pragma unroll
        for (int j = 0; j < 8; ++j) acc[i][j] = 0.f;

    const int nkb = K >> 4;
    for (int kb = 0; kb < nkb; ++kb) {
        __syncthreads();
        // stage A (128x16), store transposed [k][row]
#pragma unroll
        for (int it = 0; it < 2; ++it) {
            int idx = it * 256 + t;
            int row = idx >> 2, kq = idx & 3;
            const float4 v = *(const float4*)&A[(size_t)(row0 + row) * K + kb * 16 + kq * 4];
            a_lds[(kq * 4 + 0) * 132 + row] = v.x;
            a_lds[(kq * 4 + 1) * 132 + row] = v.y;
            a_lds[(kq * 4 + 2) * 132 + row] = v.z;
            a_lds[(kq * 4 + 3) * 132 + row] = v.w;
        }
        // stage B (16x128)
        {
            int k = t >> 4, c4 = t & 15;
#pragma unroll
            for (int it = 0; it < 2; ++it) {
                int col  = c4 * 4 + it * 64;
                int colg = col0 + col;
                float4 v = make_float4(0.f, 0.f, 0.f, 0.f);
                if (colg < N) {
                    int kg = kb * 16 + k;
                    size_t off = ZHB ? ((size_t)(colg >> 6) * (DH * DZ) + (size_t)kg * DZ + (colg & 63))
                                     : ((size_t)kg * N + colg);
                    v = *(const float4*)&Bm[off];
                }
                *(float4*)&b_lds[k * 132 + col] = v;
            }
        }
        __syncthreads();
#pragma unroll
        for (int k = 0; k < 16; ++k) {
            float4 a0 = *(const float4*)&a_lds[k * 132 + ty * 8];
            float4 a1 = *(const float4*)&a_lds[k * 132 + ty * 8 + 4];
            float4 b0 = *(const float4*)&b_lds[k * 132 + tx * 8];
            float4 b1 = *(const float4*)&b_lds[k * 132 + tx * 8 + 4];
            float av[8] = {a0.x, a0.y, a0.z, a0.w, a1.x, a1.y, a1.z, a1.w};
            float bv[8] = {b0.x, b0.y, b0.z, b0.w, b1.x, b1.y, b1.z, b1.w};
#pragma unroll
            for (int i = 0; i < 8; ++i)
#pragma unroll
                for (int j = 0; j < 8; ++j)
                    acc[i][j] = fmaf(av[i], bv[j], acc[i][j]);
        }
    }

    // epilogue
    float lsum = 0.f;
#pragma unroll
    for (int i = 0; i < 8; ++i) {
        int row = row0 + ty * 8 + i;
#pragma unroll
        for (int j = 0; j < 8; j += 4) {
            int colg = col0 + tx * 8 + j;
            if (colg < N) {
                float4 o;
                o.x = acc[i][j + 0] + bias[colg + 0];
                o.y = acc[i][j + 1] + bias[colg + 1];
                o.z = acc[i][j + 2] + bias[colg + 2];
                o.w = acc[i][j + 3] + bias[colg + 3];
                if (RELU) {
                    o.x = fmaxf(o.x, 0.f); o.y = fmaxf(o.y, 0.f);
                    o.z = fmaxf(o.z, 0.f); o.w = fmaxf(o.w, 0.f);
                }
                if (LOSS) {
                    const float4 xv = *(const float4*)&X[(size_t)row * N + colg];
                    float d0 = o.x - xv.x, d1 = o.y - xv.y, d2 = o.z - xv.z, d3 = o.w - xv.w;
                    lsum += d0 * d0 + d1 * d1 + d2 * d2 + d3 * d3;
                }
                *(float4*)&C[(size_t)row * N + colg] = o;
            }
        }
    }
    if (LOSS) {
        for (int off = 32; off; off >>= 1) lsum += __shfl_down(lsum, off);
        __shared__ float ls[4];
        if ((t & 63) == 0) ls[t >> 6] = lsum;
        __syncthreads();
        if (t == 0) atomicAdd(lacc, (double)(ls[0] + ls[1] + ls[2] + ls[3]));
    }
}

// ---------------------------------------------------------------------------
// Precompute stage 1: T1_j = postW_j @ decW1  [3][64][512]
//                     T2_p = postW_j @ preW_i [3 pairs][64][64]  (pairs (0,1),(0,2),(1,2))
//                     bq_j = postB_j @ decW1  [3][512]
//                     bp_p = postB_j @ preW_i [3][64]
// ---------------------------------------------------------------------------
__global__ __launch_bounds__(256)
void pre1_k(const float* __restrict__ postW, const float* __restrict__ postB,
            const float* __restrict__ preWf, const float* __restrict__ decW1,
            float* __restrict__ T1, float* __restrict__ T2,
            float* __restrict__ bq, float* __restrict__ bp)
{
    int id = blockIdx.x * 256 + threadIdx.x;
    const int pj[3] = {0, 0, 1}, pi[3] = {1, 2, 2};
    if (id < 98304) {                       // T1
        int j = id / 32768; int rem = id & 32767; int d = rem >> 9; int c = rem & 511;
        const float* a = postW + (size_t)j * 32768 + d * 512;
        float s = 0.f;
        for (int h = 0; h < 512; ++h) s = fmaf(a[h], decW1[h * 512 + c], s);
        T1[id] = s;
    } else if (id < 110592) {               // T2
        int e = id - 98304; int pr = e >> 12; int rem = e & 4095; int d = rem >> 6; int c = rem & 63;
        const float* a = postW + (size_t)pj[pr] * 32768 + d * 512;
        const float* w = preWf + (size_t)pi[pr] * 32768;
        float s = 0.f;
        for (int h = 0; h < 512; ++h) s = fmaf(a[h], w[h * 64 + c], s);
        T2[e] = s;
    } else if (id < 112128) {               // bq
        int e = id - 110592; int j = e >> 9; int c = e & 511;
        const float* b = postB + j * 512;
        float s = 0.f;
        for (int h = 0; h < 512; ++h) s = fmaf(b[h], decW1[h * 512 + c], s);
        bq[e] = s;
    } else if (id < 112320) {               // bp
        int e = id - 112128; int pr = e >> 6; int c = e & 63;
        const float* b = postB + pj[pr] * 512;
        const float* w = preWf + (size_t)pi[pr] * 32768;
        float s = 0.f;
        for (int h = 0; h < 512; ++h) s = fmaf(b[h], w[h * 64 + c], s);
        bp[e] = s;
    }
}

// ---------------------------------------------------------------------------
// Precompute stage 2: QD[1792][512] = cb @ T1 + bq   (post->dec1 folded)
//                     PP[2560][64]  = cb @ T2 + bp   (post->pre_i folded)
//                     cbn[1792]     = ||cb_k||^2
// ---------------------------------------------------------------------------
__global__ __launch_bounds__(256)
void pre2_k(const float* __restrict__ cb0, const float* __restrict__ cb1, const float* __restrict__ cb2,
            const float* __restrict__ T1, const float* __restrict__ T2,
            const float* __restrict__ bq, const float* __restrict__ bp,
            float* __restrict__ QD, float* __restrict__ PP, float* __restrict__ cbnv)
{
    int id = blockIdx.x * 256 + threadIdx.x;
    if (id < 917504) {                      // QD
        int kg = id >> 9, c = id & 511;
        int j = kg < 1024 ? 0 : (kg < 1536 ? 1 : 2);
        int kl = kg - (j == 0 ? 0 : (j == 1 ? 1024 : 1536));
        const float* cb = (j == 0 ? cb0 : (j == 1 ? cb1 : cb2)) + (size_t)kl * 64;
        const float* tt = T1 + (size_t)j * 32768;
        float s = bq[j * 512 + c];
        for (int d = 0; d < 64; ++d) s = fmaf(cb[d], tt[d * 512 + c], s);
        QD[id] = s;
    } else if (id < 917504 + 163840) {      // PP
        int e = id - 917504; int rg = e >> 6, c = e & 63;
        int pr = rg < 1024 ? 0 : (rg < 2048 ? 1 : 2);
        int kl = rg - (pr == 0 ? 0 : (pr == 1 ? 1024 : 2048));
        const float* cb = ((pr == 2) ? cb1 : cb0) + (size_t)kl * 64;
        const float* tt = T2 + (size_t)pr * 4096;
        float s = bp[pr * 64 + c];
        for (int d = 0; d < 64; ++d) s = fmaf(cb[d], tt[d * 64 + c], s);
        PP[e] = s;
    } else if (id < 917504 + 163840 + 1792) { // cbn
        int kg = id - 917504 - 163840;
        int j = kg < 1024 ? 0 : (kg < 1536 ? 1 : 2);
        int kl = kg - (j == 0 ? 0 : (j == 1 ? 1024 : 1536));
        const float* cb = (j == 0 ? cb0 : (j == 1 ? cb1 : cb2)) + (size_t)kl * 64;
        float s = 0.f;
        for (int d = 0; d < 64; ++d) s = fmaf(cb[d], cb[d], s);
        cbnv[kg] = s;
    }
}

// ---------------------------------------------------------------------------
// Fused VQ kernel: per block = 64 rows. 3 levels sequentially:
//   z_i = zh_i - PP corrections (via argmin ids of earlier levels),
//   dist scores vs codebook (LDS-staged, XOR-swizzled), argmin (JAX formula
//   (||z||^2 - 2 z.cb) + ||cb||^2, first-index tie-break), elementwise
//   ||q - z||^2 loss (double atomic), ids out (as float).
// Then hd = relu(sum_j QD_j[idx_j] + decB1) written for dec2.
// ---------------------------------------------------------------------------
__global__ __launch_bounds__(256)
void vq_k(const float* __restrict__ zh,
          const float* __restrict__ cb0, const float* __restrict__ cb1, const float* __restrict__ cb2,
          const float* __restrict__ cbn,
          const float* __restrict__ PP01, const float* __restrict__ PP02, const float* __restrict__ PP12,
          const float* __restrict__ QD0, const float* __restrict__ QD1, const float* __restrict__ QD2,
          const float* __restrict__ decB1,
          float* __restrict__ hd, float* __restrict__ out_ids, double* __restrict__ Sacc)
{
    __shared__ __align__(16) float z_lds[4096];   // [64][64], XOR-swizzled (bits 2..4 of d ^ row>>2)
    __shared__ __align__(16) float cb_lds[4096];  // same swizzle keyed on code row
    __shared__ float redv[1024];
    __shared__ int   redi[1024];
    __shared__ int   idx_lds[3][64];
    __shared__ float z2_lds[64];

    const int t = threadIdx.x;
    const int row0 = blockIdx.x * 64;
    const int g = t & 15, cth = t >> 4;
    const int r4 = g * 4;
    const int swz = (g & 7) << 2;     // z row-group swizzle (rows r4..r4+3 share r>>2 = g)
    const int swc = (cth & 7) << 2;   // would-be code swizzle base (per u below)

    const float* cbs[3] = {cb0, cb1, cb2};

#pragma unroll
    for (int lev = 0; lev < 3; ++lev) {
        const float* cb = cbs[lev];
        const int Kn = (lev == 0) ? 1024 : (lev == 1 ? 512 : 256);
        const float* cbnL = cbn + (lev == 0 ? 0 : (lev == 1 ? 1024 : 1536));

        // ---- phase Z: build z tile in LDS ----
        {
            int r = t >> 2, seg = t & 3;
            int sw = ((r >> 2) & 7) << 2;
            float part = 0.f;
            int i0 = (lev >= 1) ? idx_lds[0][r] : 0;
            int i1 = (lev == 2) ? idx_lds[1][r] : 0;
#pragma unroll
            for (int q = 0; q < 4; ++q) {
                int d0 = seg * 16 + q * 4;
                float4 v = *(const float4*)&zh[(size_t)(row0 + r) * 192 + lev * 64 + d0];
                if (lev == 1) {
                    const float4 p = *(const float4*)&PP01[(size_t)i0 * 64 + d0];
                    v.x -= p.x; v.y -= p.y; v.z -= p.z; v.w -= p.w;
                }
                if (lev == 2) {
                    const float4 p = *(const float4*)&PP02[(size_t)i0 * 64 + d0];
                    v.x -= p.x; v.y -= p.y; v.z -= p.z; v.w -= p.w;
                    const float4 p2 = *(const float4*)&PP12[(size_t)i1 * 64 + d0];
                    v.x -= p2.x; v.y -= p2.y; v.z -= p2.z; v.w -= p2.w;
                }
                *(float4*)&z_lds[r * 64 + (d0 ^ sw)] = v;
                part += v.x * v.x + v.y * v.y + v.z * v.z + v.w * v.w;
            }
            part += __shfl_xor(part, 1);
            part += __shfl_xor(part, 2);
            if (seg == 0) z2_lds[r] = part;
        }
        __syncthreads();

        float z2r[4];
#pragma unroll
        for (int rr = 0; rr < 4; ++rr) z2r[rr] = z2_lds[r4 + rr];

        float bestv[4] = {1e30f, 1e30f, 1e30f, 1e30f};
        int   besti[4] = {0, 0, 0, 0};

        for (int p = 0; p < Kn / 64; ++p) {
            // stage 64-code chunk of cb (swizzled)
#pragma unroll
            for (int q = 0; q < 4; ++q) {
                int flat = q * 256 + t;
                int kk = flat >> 4, d0 = (flat & 15) * 4;
                int sw = ((kk >> 2) & 7) << 2;
                *(float4*)&cb_lds[kk * 64 + (d0 ^ sw)] =
                    *(const float4*)&cb[(size_t)(p * 64 + kk) * 64 + d0];
            }
            __syncthreads();

            float a4[4][4];
#pragma unroll
            for (int rr = 0; rr < 4; ++rr)
#pragma unroll
                for (int u = 0; u < 4; ++u) a4[rr][u] = 0.f;

#pragma unroll
            for (int d4 = 0; d4 < 16; ++d4) {
                int dz = (d4 * 4) ^ swz;
                int dc = (d4 * 4) ^ swc;   // code rows cth*4..+3 share kk>>2 = cth
                float4 zr0 = *(const float4*)&z_lds[(r4 + 0) * 64 + dz];
                float4 zr1 = *(const float4*)&z_lds[(r4 + 1) * 64 + dz];
                float4 zr2 = *(const float4*)&z_lds[(r4 + 2) * 64 + dz];
                float4 zr3 = *(const float4*)&z_lds[(r4 + 3) * 64 + dz];
                float4 c0 = *(const float4*)&cb_lds[(cth * 4 + 0) * 64 + dc];
                float4 c1 = *(const float4*)&cb_lds[(cth * 4 + 1) * 64 + dc];
                float4 c2 = *(const float4*)&cb_lds[(cth * 4 + 2) * 64 + dc];
                float4 c3 = *(const float4*)&cb_lds[(cth * 4 + 3) * 64 + dc];
                float4 zrs[4] = {zr0, zr1, zr2, zr3};
                float4 cvs[4] = {c0, c1, c2, c3};
#pragma unroll
                for (int rr = 0; rr < 4; ++rr)
#pragma unroll
                    for (int u = 0; u < 4; ++u) {
                        a4[rr][u] = fmaf(zrs[rr].x, cvs[u].x, a4[rr][u]);
                        a4[rr][u] = fmaf(zrs[rr].y, cvs[u].y, a4[rr][u]);
                        a4[rr][u] = fmaf(zrs[rr].z, cvs[u].z, a4[rr][u]);
                        a4[rr][u] = fmaf(zrs[rr].w, cvs[u].w, a4[rr][u]);
                    }
            }
            // merge into running argmin (JAX dist formula)
#pragma unroll
            for (int u = 0; u < 4; ++u) {
                int k = p * 64 + cth * 4 + u;
                float cn = cbnL[k];
#pragma unroll
                for (int rr = 0; rr < 4; ++rr) {
                    float dist = (z2r[rr] - 2.f * a4[rr][u]) + cn;
                    if (dist < bestv[rr] || (dist == bestv[rr] && k < besti[rr])) {
                        bestv[rr] = dist; besti[rr] = k;
                    }
                }
            }
            __syncthreads();
        }

        // cross-thread argmin reduce per row
#pragma unroll
        for (int rr = 0; rr < 4; ++rr) {
            redv[(r4 + rr) * 16 + cth] = bestv[rr];
            redi[(r4 + rr) * 16 + cth] = besti[rr];
        }
        __syncthreads();
        if (t < 64) {
            float bv = 1e30f; int bi = 0;
#pragma unroll
            for (int c = 0; c < 16; ++c) {
                float v = redv[t * 16 + c]; int ii = redi[t * 16 + c];
                if (v < bv || (v == bv && ii < bi)) { bv = v; bi = ii; }
            }
            idx_lds[lev][t] = bi;
            // elementwise ||q - z||^2 (closer mimicry of JAX's mean((q-z)^2))
            const float* qrow = cb + (size_t)bi * 64;
            int sw = ((t >> 2) & 7) << 2;
            float ls = 0.f;
            for (int d = 0; d < 64; ++d) {
                float diff = qrow[d] - z_lds[t * 64 + (d ^ sw)];
                ls = fmaf(diff, diff, ls);
            }
            for (int off = 32; off; off >>= 1) ls += __shfl_down(ls, off);
            if (t == 0) atomicAdd(&Sacc[lev], (double)ls);
            out_ids[lev * NB + row0 + t] = (float)bi;
        }
        __syncthreads();
    }

    // ---- hd = relu(QD0[i0] + QD1[i1] + QD2[i2] + decB1) ----
    {
        int c = t * 2;
        float2 bb = *(const float2*)&decB1[c];
        for (int rr = 0; rr < 64; ++rr) {
            int i0 = idx_lds[0][rr], i1 = idx_lds[1][rr], i2 = idx_lds[2][rr];
            float2 v0 = *(const float2*)&QD0[(size_t)i0 * 512 + c];
            float2 v1 = *(const float2*)&QD1[(size_t)i1 * 512 + c];
            float2 v2 = *(const float2*)&QD2[(size_t)i2 * 512 + c];
            float ox = fmaxf(v0.x + v1.x + v2.x + bb.x, 0.f);
            float oy = fmaxf(v0.y + v1.y + v2.y + bb.y, 0.f);
            *(float2*)&hd[(size_t)(row0 + rr) * 512 + c] = make_float2(ox, oy);
        }
    }
}

__global__ void finalize_k(const double* __restrict__ Sacc, float* __restrict__ out_loss)
{
    if (threadIdx.x == 0) {
        double vq = 1.25 * (Sacc[0] + Sacc[1] + Sacc[2]) / ((double)NB * 64.0);
        double rl = Sacc[3] / ((double)NB * 768.0);
        out_loss[0] = (float)(vq + rl);
    }
}

// ---------------------------------------------------------------------------
extern "C" void kernel_launch(void* const* d_in, const int* in_sizes, int n_in,
                              void* d_out, int out_size, void* d_ws, size_t ws_size,
                              hipStream_t stream)
{
    const float* x     = (const float*)d_in[0];
    const float* encW1 = (const float*)d_in[1];
    const float* encB1 = (const float*)d_in[2];
    const float* encW2 = (const float*)d_in[3];
    const float* encB2 = (const float*)d_in[4];
    const float* preW  = (const float*)d_in[5];
    const float* preB  = (const float*)d_in[6];
    const float* cb0   = (const float*)d_in[7];
    const float* cb1   = (const float*)d_in[8];
    const float* cb2   = (const float*)d_in[9];
    const float* postW = (const float*)d_in[10];
    const float* postB = (const float*)d_in[11];
    const float* decW1 = (const float*)d_in[12];
    const float* decB1 = (const float*)d_in[13];
    const float* decW2 = (const float*)d_in[14];
    const float* decB2 = (const float*)d_in[15];

    float* ws = (float*)d_ws;
    // ws layout (float offsets)
    float* T1   = ws + 0;          // 98304
    float* T2   = ws + 98304;      // 12288
    float* bq   = ws + 110592;     // 1536
    float* bp   = ws + 112128;     // 192
    float* QD   = ws + 112320;     // 917504
    float* PP   = ws + 1029824;    // 163840
    float* cbn  = ws + 1193664;    // 1792 (ends 1195456)
    double* Sacc = (double*)(ws + 1195456); // 4 doubles (8-byte aligned: 1195456*4 % 8 == 0)
    float* h1   = ws + 1195520;    // 33554432
    float* h2   = ws + 34749952;   // 33554432
    float* zhb  = ws + 68304384;   // 12582912 (ends 80887296 floats ~= 309 MB)
    float* hd   = h1;              // alias: h1 dead after enc2

    float* outp    = (float*)d_out;
    float* out_ids = outp + (size_t)NB * DIN;            // [3][B] as float
    float* out_ls  = out_ids + (size_t)3 * NB;           // scalar

    hipMemsetAsync(Sacc, 0, 4 * sizeof(double), stream);

    pre1_k<<<439, 256, 0, stream>>>(postW, postB, preW, decW1, T1, T2, bq, bp);
    pre2_k<<<4231, 256, 0, stream>>>(cb0, cb1, cb2, T1, T2, bq, bp, QD, PP, cbn);

    // enc1: h1 = relu(x @ encW1 + encB1)
    gemm_k<true, false, false><<<dim3(4, 512), 256, 0, stream>>>(x, encW1, encB1, h1, 512, 768, nullptr, nullptr);
    // enc2: h2 = relu(h1 @ encW2 + encB2)
    gemm_k<true, false, false><<<dim3(4, 512), 256, 0, stream>>>(h1, encW2, encB2, h2, 512, 512, nullptr, nullptr);
    // zh = h2 @ preW(all 3) + preB   [B,192]
    gemm_k<false, true, false><<<dim3(2, 512), 256, 0, stream>>>(h2, preW, preB, zhb, 192, 512, nullptr, nullptr);

    vq_k<<<1024, 256, 0, stream>>>(zhb, cb0, cb1, cb2, cbn,
                                   PP, PP + 65536, PP + 131072,
                                   QD, QD + 524288, QD + 786432,
                                   decB1, hd, out_ids, Sacc);

    // dec2: recon = hd @ decW2 + decB2, fused recon-loss vs x
    gemm_k<false, false, true><<<dim3(6, 512), 256, 0, stream>>>(hd, decW2, decB2, outp, 768, 512, x, Sacc + 3);

    finalize_k<<<1, 64, 0, stream>>>(Sacc, out_ls);
}

// Round 2
// 1497.584 us; speedup vs baseline: 1.5736x; 1.5736x over previous
//
#include <hip/hip_runtime.h>
#include <hip/hip_bf16.h>

// Problem constants
#define NB 65536
#define DIN 768
#define DH 512
#define DZ 64

typedef short bf16x8 __attribute__((ext_vector_type(8)));
typedef float f32x4 __attribute__((ext_vector_type(4)));

// round-to-nearest-even fp32 -> bf16 (finite inputs)
__device__ __forceinline__ unsigned short f2bf(float a) {
    unsigned int u = __float_as_uint(a);
    unsigned int r = (u + 0x7fffu + ((u >> 16) & 1u)) >> 16;
    return (unsigned short)r;
}
__device__ __forceinline__ float bf2f(unsigned short u) {
    return __uint_as_float(((unsigned int)u) << 16);
}

// ---------------------------------------------------------------------------
// fp32-precision GEMM via split-bf16 MFMA.
// C[M,N] = A[M,K] @ W[K,N] + bias, W pre-split+transposed as WT[NSB][N][K] bf16.
// A split to NSA bf16 parts during LDS staging. Products: all (sa,sb) with
// sa+sb <= NSA-1 (6 for 3-split ~ 2^-27 repr error; 3 for 2-split ~ 2^-18).
// Block 128x128, BK=32, 4 waves (2x2), wave tile 64x64 = 4x4 MFMA 16x16x32.
// LDS rows padded to 40 bf16 (80B = 5 x 16B chunks -> conflict-free b128).
// ---------------------------------------------------------------------------
template<int NSA, int NSB, bool RELU, bool CGUARD, bool LOSS>
__global__ __launch_bounds__(256)
void gemm_mfma(const float* __restrict__ A, const unsigned short* __restrict__ WT,
               const float* __restrict__ bias, float* __restrict__ C,
               const int N, const int K,
               const float* __restrict__ X, double* __restrict__ lacc)
{
    __shared__ __align__(16) unsigned short a_lds[NSA * 128 * 40];
    __shared__ __align__(16) unsigned short b_lds[NSB * 128 * 40];
    __shared__ float ls4[4];

    const int t = threadIdx.x;
    const int lane = t & 63;
    const int w = t >> 6, wr = w >> 1, wc = w & 1;
    const int cl = lane & 15, kg = lane >> 4;
    const int row0 = blockIdx.y * 128, col0 = blockIdx.x * 128;

    f32x4 acc[4][4];
#pragma unroll
    for (int i = 0; i < 4; ++i)
#pragma unroll
        for (int j = 0; j < 4; ++j)
#pragma unroll
            for (int r = 0; r < 4; ++r) acc[i][j][r] = 0.f;

    const int nkb = K >> 5;
    for (int kb = 0; kb < nkb; ++kb) {
        const int k0 = kb * 32;
        __syncthreads();
        // ---- stage A: 128 rows x 32 k fp32 -> NSA bf16 planes ----
#pragma unroll
        for (int it = 0; it < 2; ++it) {
            int chunk = it * 256 + t;
            int row = chunk >> 2, kc = chunk & 3;
            const float* ap = A + (size_t)(row0 + row) * K + k0 + kc * 8;
            const float4 v0 = *(const float4*)ap;
            const float4 v1 = *(const float4*)(ap + 4);
            float vv[8] = {v0.x, v0.y, v0.z, v0.w, v1.x, v1.y, v1.z, v1.w};
            unsigned short sp[NSA][8];
#pragma unroll
            for (int e = 0; e < 8; ++e) {
                float a0 = vv[e];
                unsigned short h = f2bf(a0);
                sp[0][e] = h;
                if (NSA > 1) {
                    float r1 = a0 - bf2f(h);
                    unsigned short m = f2bf(r1);
                    sp[1][e] = m;
                    if (NSA > 2) sp[2][e] = f2bf(r1 - bf2f(m));
                }
            }
#pragma unroll
            for (int s = 0; s < NSA; ++s) {
                uint4 pk;
                pk.x = (unsigned)sp[s][0] | ((unsigned)sp[s][1] << 16);
                pk.y = (unsigned)sp[s][2] | ((unsigned)sp[s][3] << 16);
                pk.z = (unsigned)sp[s][4] | ((unsigned)sp[s][5] << 16);
                pk.w = (unsigned)sp[s][6] | ((unsigned)sp[s][7] << 16);
                *(uint4*)&a_lds[(s * 128 + row) * 40 + kc * 8] = pk;
            }
        }
        // ---- stage B: NSB planes of 128 cols x 32 k bf16 (pre-split) ----
#pragma unroll
        for (int it = 0; it < NSB * 2; ++it) {
            int chunk = it * 256 + t;
            int s = chunk >> 9, n = (chunk >> 2) & 127, kc = chunk & 3;
            uint4 v = make_uint4(0u, 0u, 0u, 0u);
            if (!CGUARD || (col0 + n) < N)
                v = *(const uint4*)&WT[((size_t)s * N + col0 + n) * K + k0 + kc * 8];
            *(uint4*)&b_lds[(s * 128 + n) * 40 + kc * 8] = v;
        }
        __syncthreads();

        // ---- fragments + MFMA ----
        bf16x8 af[NSA][4];
#pragma unroll
        for (int s = 0; s < NSA; ++s)
#pragma unroll
            for (int mi = 0; mi < 4; ++mi)
                af[s][mi] = *(const bf16x8*)&a_lds[(s * 128 + wr * 64 + mi * 16 + cl) * 40 + kg * 8];
#pragma unroll
        for (int sb = 0; sb < NSB; ++sb) {
            bf16x8 bfr[4];
#pragma unroll
            for (int ni = 0; ni < 4; ++ni)
                bfr[ni] = *(const bf16x8*)&b_lds[(sb * 128 + wc * 64 + ni * 16 + cl) * 40 + kg * 8];
#pragma unroll
            for (int sa = 0; sa < NSA - sb; ++sa)
#pragma unroll
                for (int mi = 0; mi < 4; ++mi)
#pragma unroll
                    for (int ni = 0; ni < 4; ++ni)
                        acc[mi][ni] = __builtin_amdgcn_mfma_f32_16x16x32_bf16(
                            af[sa][mi], bfr[ni], acc[mi][ni], 0, 0, 0);
        }
    }

    // ---- epilogue: C/D layout col = lane&15, row = (lane>>4)*4 + r ----
    float lsum = 0.f;
#pragma unroll
    for (int mi = 0; mi < 4; ++mi) {
#pragma unroll
        for (int ni = 0; ni < 4; ++ni) {
            int col = col0 + wc * 64 + ni * 16 + cl;
            if (CGUARD && col >= N) continue;
            float bb = bias[col];
#pragma unroll
            for (int r = 0; r < 4; ++r) {
                int row = row0 + wr * 64 + mi * 16 + kg * 4 + r;
                float o = acc[mi][ni][r] + bb;
                if (RELU) o = fmaxf(o, 0.f);
                if (LOSS) {
                    float d = o - X[(size_t)row * N + col];
                    lsum = fmaf(d, d, lsum);
                }
                C[(size_t)row * N + col] = o;
            }
        }
    }
    if (LOSS) {
        for (int off = 32; off; off >>= 1) lsum += __shfl_down(lsum, off);
        if ((t & 63) == 0) ls4[t >> 6] = lsum;
        __syncthreads();
        if (t == 0) atomicAdd(lacc, (double)(ls4[0] + ls4[1] + ls4[2] + ls4[3]));
    }
}

// ---------------------------------------------------------------------------
// Pre-split + transpose weights to [NS][N][K] bf16 planes.
// seg1 enc1 (512x768, 3 planes), seg2 enc2 (512x512, 3), seg3 zh (192x512, 3),
// seg4 dec2 (768x512, 2).
// ---------------------------------------------------------------------------
__global__ __launch_bounds__(256)
void split_w_k(const float* __restrict__ encW1, const float* __restrict__ encW2,
               const float* __restrict__ preW, const float* __restrict__ decW2,
               unsigned short* __restrict__ WT1, unsigned short* __restrict__ WT2,
               unsigned short* __restrict__ WTz, unsigned short* __restrict__ WTd)
{
    int id = blockIdx.x * 256 + threadIdx.x;
    if (id < 393216) {                          // enc1: n<512, k<768
        int n = id / 768, k = id - n * 768;
        float wv = encW1[(size_t)k * 512 + n];
        unsigned short h = f2bf(wv);
        float r1 = wv - bf2f(h);
        unsigned short m = f2bf(r1);
        WT1[id] = h; WT1[393216 + id] = m; WT1[786432 + id] = f2bf(r1 - bf2f(m));
    } else if (id < 655360) {                   // enc2: n<512, k<512
        int e = id - 393216; int n = e >> 9, k = e & 511;
        float wv = encW2[(size_t)k * 512 + n];
        unsigned short h = f2bf(wv);
        float r1 = wv - bf2f(h);
        unsigned short m = f2bf(r1);
        WT2[e] = h; WT2[262144 + e] = m; WT2[524288 + e] = f2bf(r1 - bf2f(m));
    } else if (id < 753664) {                   // zh: n<192 (lev*64+d), k<512
        int e = id - 655360; int n = e >> 9, k = e & 511;
        int lev = n >> 6, d = n & 63;
        float wv = preW[((size_t)lev * 512 + k) * 64 + d];
        unsigned short h = f2bf(wv);
        float r1 = wv - bf2f(h);
        unsigned short m = f2bf(r1);
        WTz[e] = h; WTz[98304 + e] = m; WTz[196608 + e] = f2bf(r1 - bf2f(m));
    } else if (id < 1146880) {                  // dec2: n<768, k<512 (2 planes)
        int e = id - 753664; int n = e >> 9, k = e & 511;
        float wv = decW2[(size_t)k * 768 + n];
        unsigned short h = f2bf(wv);
        WTd[e] = h; WTd[393216 + e] = f2bf(wv - bf2f(h));
    }
}

// ---------------------------------------------------------------------------
// Precompute stage 1 (unchanged): T1_j = postW_j @ decW1, T2_p = postW_j @ preW_i,
// bq_j = postB_j @ decW1, bp_p = postB_j @ preW_i
// ---------------------------------------------------------------------------
__global__ __launch_bounds__(256)
void pre1_k(const float* __restrict__ postW, const float* __restrict__ postB,
            const float* __restrict__ preWf, const float* __restrict__ decW1,
            float* __restrict__ T1, float* __restrict__ T2,
            float* __restrict__ bq, float* __restrict__ bp)
{
    int id = blockIdx.x * 256 + threadIdx.x;
    const int pj[3] = {0, 0, 1}, pi[3] = {1, 2, 2};
    if (id < 98304) {
        int j = id / 32768; int rem = id & 32767; int d = rem >> 9; int c = rem & 511;
        const float* a = postW + (size_t)j * 32768 + d * 512;
        float s = 0.f;
        for (int h = 0; h < 512; ++h) s = fmaf(a[h], decW1[h * 512 + c], s);
        T1[id] = s;
    } else if (id < 110592) {
        int e = id - 98304; int pr = e >> 12; int rem = e & 4095; int d = rem >> 6; int c = rem & 63;
        const float* a = postW + (size_t)pj[pr] * 32768 + d * 512;
        const float* w = preWf + (size_t)pi[pr] * 32768;
        float s = 0.f;
        for (int h = 0; h < 512; ++h) s = fmaf(a[h], w[h * 64 + c], s);
        T2[e] = s;
    } else if (id < 112128) {
        int e = id - 110592; int j = e >> 9; int c = e & 511;
        const float* b = postB + j * 512;
        float s = 0.f;
        for (int h = 0; h < 512; ++h) s = fmaf(b[h], decW1[h * 512 + c], s);
        bq[e] = s;
    } else if (id < 112320) {
        int e = id - 112128; int pr = e >> 6; int c = e & 63;
        const float* b = postB + pj[pr] * 512;
        const float* w = preWf + (size_t)pi[pr] * 32768;
        float s = 0.f;
        for (int h = 0; h < 512; ++h) s = fmaf(b[h], w[h * 64 + c], s);
        bp[e] = s;
    }
}

// ---------------------------------------------------------------------------
// Precompute stage 2 (unchanged): QD = cb @ T1 + bq, PP = cb @ T2 + bp, cbn
// ---------------------------------------------------------------------------
__global__ __launch_bounds__(256)
void pre2_k(const float* __restrict__ cb0, const float* __restrict__ cb1, const float* __restrict__ cb2,
            const float* __restrict__ T1, const float* __restrict__ T2,
            const float* __restrict__ bq, const float* __restrict__ bp,
            float* __restrict__ QD, float* __restrict__ PP, float* __restrict__ cbnv)
{
    int id = blockIdx.x * 256 + threadIdx.x;
    if (id < 917504) {
        int kg = id >> 9, c = id & 511;
        int j = kg < 1024 ? 0 : (kg < 1536 ? 1 : 2);
        int kl = kg - (j == 0 ? 0 : (j == 1 ? 1024 : 1536));
        const float* cb = (j == 0 ? cb0 : (j == 1 ? cb1 : cb2)) + (size_t)kl * 64;
        const float* tt = T1 + (size_t)j * 32768;
        float s = bq[j * 512 + c];
        for (int d = 0; d < 64; ++d) s = fmaf(cb[d], tt[d * 512 + c], s);
        QD[id] = s;
    } else if (id < 917504 + 163840) {
        int e = id - 917504; int rg = e >> 6, c = e & 63;
        int pr = rg < 1024 ? 0 : (rg < 2048 ? 1 : 2);
        int kl = rg - (pr == 0 ? 0 : (pr == 1 ? 1024 : 2048));
        const float* cb = ((pr == 2) ? cb1 : cb0) + (size_t)kl * 64;
        const float* tt = T2 + (size_t)pr * 4096;
        float s = bp[pr * 64 + c];
        for (int d = 0; d < 64; ++d) s = fmaf(cb[d], tt[d * 64 + c], s);
        PP[e] = s;
    } else if (id < 917504 + 163840 + 1792) {
        int kg = id - 917504 - 163840;
        int j = kg < 1024 ? 0 : (kg < 1536 ? 1 : 2);
        int kl = kg - (j == 0 ? 0 : (j == 1 ? 1024 : 1536));
        const float* cb = (j == 0 ? cb0 : (j == 1 ? cb1 : cb2)) + (size_t)kl * 64;
        float s = 0.f;
        for (int d = 0; d < 64; ++d) s = fmaf(cb[d], cb[d], s);
        cbnv[kg] = s;
    }
}

// ---------------------------------------------------------------------------
// Fused VQ kernel (unchanged from R1 — verified correct)
// ---------------------------------------------------------------------------
__global__ __launch_bounds__(256)
void vq_k(const float* __restrict__ zh,
          const float* __restrict__ cb0, const float* __restrict__ cb1, const float* __restrict__ cb2,
          const float* __restrict__ cbn,
          const float* __restrict__ PP01, const float* __restrict__ PP02, const float* __restrict__ PP12,
          const float* __restrict__ QD0, const float* __restrict__ QD1, const float* __restrict__ QD2,
          const float* __restrict__ decB1,
          float* __restrict__ hd, float* __restrict__ out_ids, double* __restrict__ Sacc)
{
    __shared__ __align__(16) float z_lds[4096];
    __shared__ __align__(16) float cb_lds[4096];
    __shared__ float redv[1024];
    __shared__ int   redi[1024];
    __shared__ int   idx_lds[3][64];
    __shared__ float z2_lds[64];

    const int t = threadIdx.x;
    const int row0 = blockIdx.x * 64;
    const int g = t & 15, cth = t >> 4;
    const int r4 = g * 4;
    const int swz = (g & 7) << 2;
    const int swc = (cth & 7) << 2;

    const float* cbs[3] = {cb0, cb1, cb2};

#pragma unroll
    for (int lev = 0; lev < 3; ++lev) {
        const float* cb = cbs[lev];
        const int Kn = (lev == 0) ? 1024 : (lev == 1 ? 512 : 256);
        const float* cbnL = cbn + (lev == 0 ? 0 : (lev == 1 ? 1024 : 1536));

        {
            int r = t >> 2, seg = t & 3;
            int sw = ((r >> 2) & 7) << 2;
            float part = 0.f;
            int i0 = (lev >= 1) ? idx_lds[0][r] : 0;
            int i1 = (lev == 2) ? idx_lds[1][r] : 0;
#pragma unroll
            for (int q = 0; q < 4; ++q) {
                int d0 = seg * 16 + q * 4;
                float4 v = *(const float4*)&zh[(size_t)(row0 + r) * 192 + lev * 64 + d0];
                if (lev == 1) {
                    const float4 p = *(const float4*)&PP01[(size_t)i0 * 64 + d0];
                    v.x -= p.x; v.y -= p.y; v.z -= p.z; v.w -= p.w;
                }
                if (lev == 2) {
                    const float4 p = *(const float4*)&PP02[(size_t)i0 * 64 + d0];
                    v.x -= p.x; v.y -= p.y; v.z -= p.z; v.w -= p.w;
                    const float4 p2 = *(const float4*)&PP12[(size_t)i1 * 64 + d0];
                    v.x -= p2.x; v.y -= p2.y; v.z -= p2.z; v.w -= p2.w;
                }
                *(float4*)&z_lds[r * 64 + (d0 ^ sw)] = v;
                part += v.x * v.x + v.y * v.y + v.z * v.z + v.w * v.w;
            }
            part += __shfl_xor(part, 1);
            part += __shfl_xor(part, 2);
            if (seg == 0) z2_lds[r] = part;
        }
        __syncthreads();

        float z2r[4];
#pragma unroll
        for (int rr = 0; rr < 4; ++rr) z2r[rr] = z2_lds[r4 + rr];

        float bestv[4] = {1e30f, 1e30f, 1e30f, 1e30f};
        int   besti[4] = {0, 0, 0, 0};

        for (int p = 0; p < Kn / 64; ++p) {
#pragma unroll
            for (int q = 0; q < 4; ++q) {
                int flat = q * 256 + t;
                int kk = flat >> 4, d0 = (flat & 15) * 4;
                int sw = ((kk >> 2) & 7) << 2;
                *(float4*)&cb_lds[kk * 64 + (d0 ^ sw)] =
                    *(const float4*)&cb[(size_t)(p * 64 + kk) * 64 + d0];
            }
            __syncthreads();

            float a4[4][4];
#pragma unroll
            for (int rr = 0; rr < 4; ++rr)
#pragma unroll
                for (int u = 0; u < 4; ++u) a4[rr][u] = 0.f;

#pragma unroll
            for (int d4 = 0; d4 < 16; ++d4) {
                int dz = (d4 * 4) ^ swz;
                int dc = (d4 * 4) ^ swc;
                float4 zr0 = *(const float4*)&z_lds[(r4 + 0) * 64 + dz];
                float4 zr1 = *(const float4*)&z_lds[(r4 + 1) * 64 + dz];
                float4 zr2 = *(const float4*)&z_lds[(r4 + 2) * 64 + dz];
                float4 zr3 = *(const float4*)&z_lds[(r4 + 3) * 64 + dz];
                float4 c0 = *(const float4*)&cb_lds[(cth * 4 + 0) * 64 + dc];
                float4 c1 = *(const float4*)&cb_lds[(cth * 4 + 1) * 64 + dc];
                float4 c2 = *(const float4*)&cb_lds[(cth * 4 + 2) * 64 + dc];
                float4 c3 = *(const float4*)&cb_lds[(cth * 4 + 3) * 64 + dc];
                float4 zrs[4] = {zr0, zr1, zr2, zr3};
                float4 cvs[4] = {c0, c1, c2, c3};
#pragma unroll
                for (int rr = 0; rr < 4; ++rr)
#pragma unroll
                    for (int u = 0; u < 4; ++u) {
                        a4[rr][u] = fmaf(zrs[rr].x, cvs[u].x, a4[rr][u]);
                        a4[rr][u] = fmaf(zrs[rr].y, cvs[u].y, a4[rr][u]);
                        a4[rr][u] = fmaf(zrs[rr].z, cvs[u].z, a4[rr][u]);
                        a4[rr][u] = fmaf(zrs[rr].w, cvs[u].w, a4[rr][u]);
                    }
            }
#pragma unroll
            for (int u = 0; u < 4; ++u) {
                int k = p * 64 + cth * 4 + u;
                float cn = cbnL[k];
#pragma unroll
                for (int rr = 0; rr < 4; ++rr) {
                    float dist = (z2r[rr] - 2.f * a4[rr][u]) + cn;
                    if (dist < bestv[rr] || (dist == bestv[rr] && k < besti[rr])) {
                        bestv[rr] = dist; besti[rr] = k;
                    }
                }
            }
            __syncthreads();
        }

#pragma unroll
        for (int rr = 0; rr < 4; ++rr) {
            redv[(r4 + rr) * 16 + cth] = bestv[rr];
            redi[(r4 + rr) * 16 + cth] = besti[rr];
        }
        __syncthreads();
        if (t < 64) {
            float bv = 1e30f; int bi = 0;
#pragma unroll
            for (int c = 0; c < 16; ++c) {
                float v = redv[t * 16 + c]; int ii = redi[t * 16 + c];
                if (v < bv || (v == bv && ii < bi)) { bv = v; bi = ii; }
            }
            idx_lds[lev][t] = bi;
            const float* qrow = cb + (size_t)bi * 64;
            int sw = ((t >> 2) & 7) << 2;
            float ls = 0.f;
            for (int d = 0; d < 64; ++d) {
                float diff = qrow[d] - z_lds[t * 64 + (d ^ sw)];
                ls = fmaf(diff, diff, ls);
            }
            for (int off = 32; off; off >>= 1) ls += __shfl_down(ls, off);
            if (t == 0) atomicAdd(&Sacc[lev], (double)ls);
            out_ids[lev * NB + row0 + t] = (float)bi;
        }
        __syncthreads();
    }

    {
        int c = t * 2;
        float2 bb = *(const float2*)&decB1[c];
        for (int rr = 0; rr < 64; ++rr) {
            int i0 = idx_lds[0][rr], i1 = idx_lds[1][rr], i2 = idx_lds[2][rr];
            float2 v0 = *(const float2*)&QD0[(size_t)i0 * 512 + c];
            float2 v1 = *(const float2*)&QD1[(size_t)i1 * 512 + c];
            float2 v2 = *(const float2*)&QD2[(size_t)i2 * 512 + c];
            float ox = fmaxf(v0.x + v1.x + v2.x + bb.x, 0.f);
            float oy = fmaxf(v0.y + v1.y + v2.y + bb.y, 0.f);
            *(float2*)&hd[(size_t)(row0 + rr) * 512 + c] = make_float2(ox, oy);
        }
    }
}

__global__ void finalize_k(const double* __restrict__ Sacc, float* __restrict__ out_loss)
{
    if (threadIdx.x == 0) {
        double vq = 1.25 * (Sacc[0] + Sacc[1] + Sacc[2]) / ((double)NB * 64.0);
        double rl = Sacc[3] / ((double)NB * 768.0);
        out_loss[0] = (float)(vq + rl);
    }
}

// ---------------------------------------------------------------------------
extern "C" void kernel_launch(void* const* d_in, const int* in_sizes, int n_in,
                              void* d_out, int out_size, void* d_ws, size_t ws_size,
                              hipStream_t stream)
{
    const float* x     = (const float*)d_in[0];
    const float* encW1 = (const float*)d_in[1];
    const float* encB1 = (const float*)d_in[2];
    const float* encW2 = (const float*)d_in[3];
    const float* encB2 = (const float*)d_in[4];
    const float* preW  = (const float*)d_in[5];
    const float* preB  = (const float*)d_in[6];
    const float* cb0   = (const float*)d_in[7];
    const float* cb1   = (const float*)d_in[8];
    const float* cb2   = (const float*)d_in[9];
    const float* postW = (const float*)d_in[10];
    const float* postB = (const float*)d_in[11];
    const float* decW1 = (const float*)d_in[12];
    const float* decB1 = (const float*)d_in[13];
    const float* decW2 = (const float*)d_in[14];
    const float* decB2 = (const float*)d_in[15];

    float* ws = (float*)d_ws;
    float* T1   = ws + 0;          // 98304
    float* T2   = ws + 98304;      // 12288
    float* bq   = ws + 110592;     // 1536
    float* bp   = ws + 112128;     // 192
    float* QD   = ws + 112320;     // 917504
    float* PP   = ws + 1029824;    // 163840
    float* cbn  = ws + 1193664;    // 1792
    double* Sacc = (double*)(ws + 1195456); // 4 doubles
    unsigned short* WTb = (unsigned short*)(ws + 1195520);
    unsigned short* WT1 = WTb;               // 1179648 u16
    unsigned short* WT2 = WTb + 1179648;     // 786432
    unsigned short* WTz = WTb + 1966080;     // 294912
    unsigned short* WTd = WTb + 2260992;     // 786432 (ends 3047424 u16 = 1523712 f)
    float* h1   = ws + 2719232;    // 33554432
    float* h2   = ws + 36273664;   // 33554432
    float* zhb  = ws + 69828096;   // 12582912 (ends 82411008 floats ~= 330 MB)
    float* hd   = h1;              // h1 dead after enc2

    float* outp    = (float*)d_out;
    float* out_ids = outp + (size_t)NB * DIN;
    float* out_ls  = out_ids + (size_t)3 * NB;

    hipMemsetAsync(Sacc, 0, 4 * sizeof(double), stream);

    split_w_k<<<4480, 256, 0, stream>>>(encW1, encW2, preW, decW2, WT1, WT2, WTz, WTd);
    pre1_k<<<439, 256, 0, stream>>>(postW, postB, preW, decW1, T1, T2, bq, bp);
    pre2_k<<<4231, 256, 0, stream>>>(cb0, cb1, cb2, T1, T2, bq, bp, QD, PP, cbn);

    // enc1: h1 = relu(x @ encW1 + encB1)  -- 6-product fp32-emu
    gemm_mfma<3, 3, true, false, false><<<dim3(4, 512), 256, 0, stream>>>(
        x, WT1, encB1, h1, 512, 768, nullptr, nullptr);
    // enc2: h2 = relu(h1 @ encW2 + encB2)
    gemm_mfma<3, 3, true, false, false><<<dim3(4, 512), 256, 0, stream>>>(
        h1, WT2, encB2, h2, 512, 512, nullptr, nullptr);
    // zh = h2 @ preW(all) + preB   [B,192], col-guarded
    gemm_mfma<3, 3, false, true, false><<<dim3(2, 512), 256, 0, stream>>>(
        h2, WTz, preB, zhb, 192, 512, nullptr, nullptr);

    vq_k<<<1024, 256, 0, stream>>>(zhb, cb0, cb1, cb2, cbn,
                                   PP, PP + 65536, PP + 131072,
                                   QD, QD + 524288, QD + 786432,
                                   decB1, hd, out_ids, Sacc);

    // dec2: recon = hd @ decW2 + decB2 (+fused loss) -- 3-product (downstream of argmin)
    gemm_mfma<2, 2, false, false, true><<<dim3(6, 512), 256, 0, stream>>>(
        hd, WTd, decB2, outp, 768, 512, x, Sacc + 3);

    finalize_k<<<1, 64, 0, stream>>>(Sacc, out_ls);
}